// Round 1
// baseline (5290.121 us; speedup 1.0000x reference)
//
#include <hip/hip_runtime.h>
#include <hip/hip_fp16.h>
#include <math.h>

#define NUM_LAYERS 6
#define DM 1024
#define NH 16
#define DH 64
#define MAX_SEQ 4096
#define DFF 4096
#define LSEQ 544
#define TTOK 512
#define LATENT 32

static __device__ __forceinline__ float wave_sum(float v) {
#pragma unroll
    for (int off = 32; off > 0; off >>= 1) v += __shfl_xor(v, off, 64);
    return v;
}

// ---- build x: rows 0..511 copy text, rows 512..543 = seq @ W_in + b_in ----
__global__ __launch_bounds__(256) void build_x_kernel(
    const float* __restrict__ text, const float* __restrict__ seq,
    const float* __restrict__ bos, const float* __restrict__ W_in,
    const float* __restrict__ b_in, float* __restrict__ x)
{
    const int l = blockIdx.x, tid = threadIdx.x;
    if (l < TTOK) {
        const float4* src = (const float4*)(text + (size_t)l * DM);
        float4* dst = (float4*)(x + (size_t)l * DM);
        dst[tid] = src[tid];  // 256 * float4 = 1024 floats
    } else {
        __shared__ float s[LATENT];
        const int r = l - TTOK;
        if (tid < LATENT) {
            float v = seq[r * LATENT + tid];
            s[tid] = (v != v) ? bos[tid] : v;  // NaN -> bos_emb
        }
        __syncthreads();
        for (int c = tid; c < DM; c += 256) {
            float acc = b_in[c];
#pragma unroll
            for (int k = 0; k < LATENT; ++k) acc = fmaf(s[k], W_in[k * DM + c], acc);
            x[(size_t)l * DM + c] = acc;
        }
    }
}

// ---- layernorm over rows of [LSEQ, 1024] ----
__global__ __launch_bounds__(256) void ln_kernel(
    const float* __restrict__ in, const float* __restrict__ w,
    const float* __restrict__ b, float* __restrict__ out)
{
    const int l = blockIdx.x, tid = threadIdx.x;
    const float4 v = *(const float4*)(in + (size_t)l * DM + tid * 4);
    float s = v.x + v.y + v.z + v.w;
    float ss = v.x * v.x + v.y * v.y + v.z * v.z + v.w * v.w;
    s = wave_sum(s); ss = wave_sum(ss);
    __shared__ float ls[4], lss[4];
    const int wid = tid >> 6;
    if ((tid & 63) == 0) { ls[wid] = s; lss[wid] = ss; }
    __syncthreads();
    const float mu = (ls[0] + ls[1] + ls[2] + ls[3]) * (1.0f / DM);
    const float var = (lss[0] + lss[1] + lss[2] + lss[3]) * (1.0f / DM) - mu * mu;
    const float rstd = rsqrtf(var + 1e-5f);
    const float4 wv = *(const float4*)(w + tid * 4);
    const float4 bv = *(const float4*)(b + tid * 4);
    float4 o;
    o.x = (v.x - mu) * rstd * wv.x + bv.x;
    o.y = (v.y - mu) * rstd * wv.y + bv.y;
    o.z = (v.z - mu) * rstd * wv.z + bv.z;
    o.w = (v.w - mu) * rstd * wv.w + bv.w;
    *(float4*)(out + (size_t)l * DM + tid * 4) = o;
}

// ---- fp32 tiled GEMM: C[M,N] = act(A[M,K] @ B[K,N] + bias) + residual ----
// 64x64 tile, BK=16, 256 threads, 4x4 per thread
__global__ __launch_bounds__(256) void gemm_kernel(
    const float* __restrict__ A, const float* __restrict__ B,
    float* __restrict__ C, const float* __restrict__ bias,
    const float* __restrict__ residual, int M, int N, int K, int act)
{
    __shared__ float As[16][64];
    __shared__ float Bs[16][68];
    const int tid = threadIdx.x;
    const int tx = tid & 15, ty = tid >> 4;
    const int m0 = blockIdx.y << 6, n0 = blockIdx.x << 6;
    const int arow = tid & 63, akq = (tid >> 6) << 2;
    const int bk = tid >> 4, bn = (tid & 15) << 2;
    float acc[4][4] = {{0.f, 0.f, 0.f, 0.f}};
    for (int k0 = 0; k0 < K; k0 += 16) {
        float4 av = make_float4(0.f, 0.f, 0.f, 0.f);
        const int gm = m0 + arow;
        if (gm < M) av = *(const float4*)(A + (size_t)gm * K + k0 + akq);
        As[akq + 0][arow] = av.x;
        As[akq + 1][arow] = av.y;
        As[akq + 2][arow] = av.z;
        As[akq + 3][arow] = av.w;
        *(float4*)&Bs[bk][bn] = *(const float4*)(B + (size_t)(k0 + bk) * N + n0 + bn);
        __syncthreads();
#pragma unroll
        for (int kk = 0; kk < 16; ++kk) {
            const float4 a4 = *(const float4*)&As[kk][ty << 2];
            const float4 b4 = *(const float4*)&Bs[kk][tx << 2];
            const float a[4] = {a4.x, a4.y, a4.z, a4.w};
            const float bb[4] = {b4.x, b4.y, b4.z, b4.w};
#pragma unroll
            for (int i = 0; i < 4; ++i)
#pragma unroll
                for (int j = 0; j < 4; ++j)
                    acc[i][j] = fmaf(a[i], bb[j], acc[i][j]);
        }
        __syncthreads();
    }
    const bool has_bias = bias != nullptr;
    const bool has_res = residual != nullptr;
#pragma unroll
    for (int i = 0; i < 4; ++i) {
        const int r = m0 + (ty << 2) + i;
        if (r < M) {
#pragma unroll
            for (int j = 0; j < 4; ++j) {
                const int c = n0 + (tx << 2) + j;
                float val = acc[i][j];
                if (has_bias) val += bias[c];
                if (act) val = 0.5f * val * (1.0f + erff(val * 0.70710678118654752f));
                if (has_res) val += residual[(size_t)r * N + c];
                C[(size_t)r * N + c] = val;
            }
        }
    }
}

// ---- convert full input fp16 caches to f32 output regions ----
__global__ __launch_bounds__(256) void cache_convert_kernel(
    const __half2* __restrict__ kin, const __half2* __restrict__ vin,
    float2* __restrict__ kout, float2* __restrict__ vout, int n2)
{
    int i = blockIdx.x * 256 + threadIdx.x;
    const int stride = gridDim.x * 256;
    for (; i < n2; i += stride) {
        kout[i] = __half22float2(kin[i]);
        vout[i] = __half22float2(vin[i]);
    }
}

// ---- split qkv row, RoPE q/k, fp16-round k/v into cache (stored f32) ----
__global__ __launch_bounds__(256) void rope_store_kernel(
    const float* __restrict__ qkv, float* __restrict__ q_buf,
    float* __restrict__ k_out, float* __restrict__ v_out,
    const int* __restrict__ steps, int layer)
{
    const int l = blockIdx.x, tid = threadIdx.x;
    const int offset = steps[layer];
    const int pos = offset + l;
    const float t = (float)pos;
    const float* base = qkv + (size_t)l * 3 * DM;
    for (int p = tid; p < NH * (DH / 2); p += 256) {
        const int h = p >> 5, j = p & 31;
        const float freq = powf(10000.0f, -(float)j / 32.0f);
        float sn, cs;
        sincosf(t * freq, &sn, &cs);
        const int e = h * DH + 2 * j;
        const float q1 = base[e], q2 = base[e + 1];
        q_buf[(size_t)l * DM + e]     = q1 * cs - q2 * sn;
        q_buf[(size_t)l * DM + e + 1] = q1 * sn + q2 * cs;
        const float k1 = base[DM + e], k2 = base[DM + e + 1];
        const size_t co = (size_t)pos * DM + e;
        k_out[co]     = __half2float(__float2half(k1 * cs - k2 * sn));
        k_out[co + 1] = __half2float(__float2half(k1 * sn + k2 * cs));
    }
    for (int e = tid; e < DM; e += 256) {
        v_out[(size_t)pos * DM + e] = __half2float(__float2half(base[2 * DM + e]));
    }
}

// ---- causal attention, one wave per (query l, head h), online softmax ----
__global__ __launch_bounds__(64) void attn_kernel(
    const float* __restrict__ q_buf, const float* __restrict__ kc,
    const float* __restrict__ vc, float* __restrict__ attn_out,
    const int* __restrict__ steps, int layer)
{
    const int l = blockIdx.x, h = blockIdx.y, lane = threadIdx.x;
    const int qpos = steps[layer] + l;
    const float qv = q_buf[(size_t)l * DM + h * DH + lane];
    float m = -INFINITY, lsum = 0.0f, acc = 0.0f;
    for (int s = 0; s <= qpos; ++s) {
        const size_t idx = (size_t)s * DM + h * DH + lane;
        float p = qv * kc[idx];
        p = wave_sum(p);
        const float score = p * 0.125f;  // 1/sqrt(64)
        const float mn = fmaxf(m, score);
        const float corr = __expf(m - mn);
        const float wgt = __expf(score - mn);
        lsum = lsum * corr + wgt;
        acc = acc * corr + wgt * vc[idx];
        m = mn;
    }
    attn_out[(size_t)l * DM + h * DH + lane] = acc / lsum;
}

// ---- final LN of last row + eos logit + new_steps ----
__global__ __launch_bounds__(256) void final_kernel(
    const float* __restrict__ x, const float* __restrict__ w,
    const float* __restrict__ b, const float* __restrict__ W_eos,
    const float* __restrict__ b_eos, const int* __restrict__ steps,
    float* __restrict__ out, size_t steps_off)
{
    const int tid = threadIdx.x;
    const float4 v = *(const float4*)(x + (size_t)(LSEQ - 1) * DM + tid * 4);
    float s = v.x + v.y + v.z + v.w;
    float ss = v.x * v.x + v.y * v.y + v.z * v.z + v.w * v.w;
    s = wave_sum(s); ss = wave_sum(ss);
    __shared__ float ls[4], lss[4], ds[4];
    const int wid = tid >> 6;
    if ((tid & 63) == 0) { ls[wid] = s; lss[wid] = ss; }
    __syncthreads();
    const float mu = (ls[0] + ls[1] + ls[2] + ls[3]) * (1.0f / DM);
    const float var = (lss[0] + lss[1] + lss[2] + lss[3]) * (1.0f / DM) - mu * mu;
    const float rstd = rsqrtf(var + 1e-5f);
    const float4 wv = *(const float4*)(w + tid * 4);
    const float4 bv = *(const float4*)(b + tid * 4);
    float4 o;
    o.x = (v.x - mu) * rstd * wv.x + bv.x;
    o.y = (v.y - mu) * rstd * wv.y + bv.y;
    o.z = (v.z - mu) * rstd * wv.z + bv.z;
    o.w = (v.w - mu) * rstd * wv.w + bv.w;
    *(float4*)(out + tid * 4) = o;
    const float4 we = *(const float4*)(W_eos + tid * 4);
    float pd = o.x * we.x + o.y * we.y + o.z * we.z + o.w * we.w;
    pd = wave_sum(pd);
    if ((tid & 63) == 0) ds[wid] = pd;
    __syncthreads();
    if (tid == 0) out[DM] = ds[0] + ds[1] + ds[2] + ds[3] + b_eos[0];
    if (tid < NUM_LAYERS) out[steps_off + tid] = (float)(steps[tid] + LSEQ);
}

extern "C" void kernel_launch(void* const* d_in, const int* in_sizes, int n_in,
                              void* d_out, int out_size, void* d_ws, size_t ws_size,
                              hipStream_t stream)
{
    (void)in_sizes; (void)n_in; (void)out_size; (void)ws_size;
    const float* sequence = (const float*)d_in[0];
    const float* text     = (const float*)d_in[1];
    const __half* k_caches = (const __half*)d_in[2];
    const __half* v_caches = (const __half*)d_in[3];
    const int* steps      = (const int*)d_in[4];
    const float* bos      = (const float*)d_in[5];
    const float* W_in     = (const float*)d_in[6];
    const float* b_in     = (const float*)d_in[7];
    const float* ln1_w    = (const float*)d_in[8];
    const float* ln1_b    = (const float*)d_in[9];
    const float* Wqkv     = (const float*)d_in[10];
    const float* Wo       = (const float*)d_in[11];
    const float* ln2_w    = (const float*)d_in[12];
    const float* ln2_b    = (const float*)d_in[13];
    const float* W1       = (const float*)d_in[14];
    const float* b1       = (const float*)d_in[15];
    const float* W2       = (const float*)d_in[16];
    const float* b2       = (const float*)d_in[17];
    const float* outn_w   = (const float*)d_in[18];
    const float* outn_b   = (const float*)d_in[19];
    const float* W_eos    = (const float*)d_in[20];
    const float* b_eos    = (const float*)d_in[21];

    float* out = (float*)d_out;
    const size_t cacheN = (size_t)NUM_LAYERS * MAX_SEQ * DM;  // 25165824
    float* out_k = out + 1025;
    float* out_v = out_k + cacheN;
    const size_t steps_off = 1025 + 2 * cacheN;

    float* ws = (float*)d_ws;
    float* x        = ws;                            // 544*1024
    float* h        = x + (size_t)LSEQ * DM;         // 544*1024
    float* q_buf    = h + (size_t)LSEQ * DM;         // 544*1024
    float* attn_out = q_buf + (size_t)LSEQ * DM;     // 544*1024
    float* big      = attn_out + (size_t)LSEQ * DM;  // 544*4096 (qkv / ff1)

    cache_convert_kernel<<<2048, 256, 0, stream>>>(
        (const __half2*)k_caches, (const __half2*)v_caches,
        (float2*)out_k, (float2*)out_v, (int)(cacheN / 2));
    build_x_kernel<<<LSEQ, 256, 0, stream>>>(text, sequence, bos, W_in, b_in, x);

    for (int i = 0; i < NUM_LAYERS; ++i) {
        float* kci = out_k + (size_t)i * MAX_SEQ * DM;
        float* vci = out_v + (size_t)i * MAX_SEQ * DM;
        ln_kernel<<<LSEQ, 256, 0, stream>>>(x, ln1_w + i * DM, ln1_b + i * DM, h);
        gemm_kernel<<<dim3(48, 9), 256, 0, stream>>>(
            h, Wqkv + (size_t)i * DM * 3 * DM, big, nullptr, nullptr, LSEQ, 3 * DM, DM, 0);
        rope_store_kernel<<<LSEQ, 256, 0, stream>>>(big, q_buf, kci, vci, steps, i);
        attn_kernel<<<dim3(LSEQ, NH), 64, 0, stream>>>(q_buf, kci, vci, attn_out, steps, i);
        gemm_kernel<<<dim3(16, 9), 256, 0, stream>>>(
            attn_out, Wo + (size_t)i * DM * DM, x, nullptr, x, LSEQ, DM, DM, 0);
        ln_kernel<<<LSEQ, 256, 0, stream>>>(x, ln2_w + i * DM, ln2_b + i * DM, h);
        gemm_kernel<<<dim3(64, 9), 256, 0, stream>>>(
            h, W1 + (size_t)i * DM * DFF, big, b1 + i * DFF, nullptr, LSEQ, DFF, DM, 1);
        gemm_kernel<<<dim3(16, 9), 256, 0, stream>>>(
            big, W2 + (size_t)i * DFF * DM, x, b2 + i * DM, x, LSEQ, DM, DFF, 0);
    }
    final_kernel<<<1, 256, 0, stream>>>(x, outn_w, outn_b, W_eos, b_eos, steps, out, steps_off);
}

// Round 2
// 4144.728 us; speedup vs baseline: 1.2763x; 1.2763x over previous
//
#include <hip/hip_runtime.h>
#include <hip/hip_fp16.h>
#include <math.h>

#define NUM_LAYERS 6
#define DM 1024
#define NH 16
#define DH 64
#define MAX_SEQ 4096
#define DFF 4096
#define LSEQ 544
#define TTOK 512
#define LATENT 32

typedef __bf16 bf16x8 __attribute__((ext_vector_type(8)));
typedef float floatx4 __attribute__((ext_vector_type(4)));

static __device__ __forceinline__ float wave_sum(float v) {
#pragma unroll
    for (int off = 32; off > 0; off >>= 1) v += __shfl_xor(v, off, 64);
    return v;
}

// ---- build x: rows 0..511 copy text, rows 512..543 = seq @ W_in + b_in ----
__global__ __launch_bounds__(256) void build_x_kernel(
    const float* __restrict__ text, const float* __restrict__ seq,
    const float* __restrict__ bos, const float* __restrict__ W_in,
    const float* __restrict__ b_in, float* __restrict__ x)
{
    const int l = blockIdx.x, tid = threadIdx.x;
    if (l < TTOK) {
        const float4* src = (const float4*)(text + (size_t)l * DM);
        float4* dst = (float4*)(x + (size_t)l * DM);
        dst[tid] = src[tid];
    } else {
        __shared__ float s[LATENT];
        const int r = l - TTOK;
        if (tid < LATENT) {
            float v = seq[r * LATENT + tid];
            s[tid] = (v != v) ? bos[tid] : v;  // NaN -> bos_emb
        }
        __syncthreads();
        for (int c = tid; c < DM; c += 256) {
            float acc = b_in[c];
#pragma unroll
            for (int k = 0; k < LATENT; ++k) acc = fmaf(s[k], W_in[k * DM + c], acc);
            x[(size_t)l * DM + c] = acc;
        }
    }
}

// ---- layernorm over rows of [LSEQ, 1024] ----
__global__ __launch_bounds__(256) void ln_kernel(
    const float* __restrict__ in, const float* __restrict__ w,
    const float* __restrict__ b, float* __restrict__ out)
{
    const int l = blockIdx.x, tid = threadIdx.x;
    const float4 v = *(const float4*)(in + (size_t)l * DM + tid * 4);
    float s = v.x + v.y + v.z + v.w;
    float ss = v.x * v.x + v.y * v.y + v.z * v.z + v.w * v.w;
    s = wave_sum(s); ss = wave_sum(ss);
    __shared__ float ls[4], lss[4];
    const int wid = tid >> 6;
    if ((tid & 63) == 0) { ls[wid] = s; lss[wid] = ss; }
    __syncthreads();
    const float mu = (ls[0] + ls[1] + ls[2] + ls[3]) * (1.0f / DM);
    const float var = (lss[0] + lss[1] + lss[2] + lss[3]) * (1.0f / DM) - mu * mu;
    const float rstd = rsqrtf(var + 1e-5f);
    const float4 wv = *(const float4*)(w + tid * 4);
    const float4 bv = *(const float4*)(b + tid * 4);
    float4 o;
    o.x = (v.x - mu) * rstd * wv.x + bv.x;
    o.y = (v.y - mu) * rstd * wv.y + bv.y;
    o.z = (v.z - mu) * rstd * wv.z + bv.z;
    o.w = (v.w - mu) * rstd * wv.w + bv.w;
    *(float4*)(out + (size_t)l * DM + tid * 4) = o;
}

// ---- bf16 MFMA GEMM: C[M,N] = act(A[M,K]@B[K,N] + bias) + residual ----
// 128x128 tile, BK=32, 256 threads = 4 waves, each wave 64x64 via 4x4 MFMA
__global__ __launch_bounds__(256) void gemm_mfma_kernel(
    const float* __restrict__ A, const float* __restrict__ B,
    float* __restrict__ C, const float* __restrict__ bias,
    const float* __restrict__ residual, int M, int N, int K, int act)
{
    // stride 40 bf16 = 80 B per row: keeps b128 rows spread across banks
    __shared__ __bf16 As[128 * 40];
    __shared__ __bf16 Bs[128 * 40];
    const int tid = threadIdx.x;
    const int m0 = blockIdx.y << 7, n0 = blockIdx.x << 7;
    const int w = tid >> 6, lane = tid & 63;
    const int wm = (w >> 1) << 6, wn = (w & 1) << 6;
    const int q = lane >> 4, mr = lane & 15;

    floatx4 acc[4][4] = {};

    const int ar = tid >> 1;            // A-row within tile, 0..127
    const int ac0 = (tid & 1) << 1;     // A chunks {0,1} or {2,3}
    const int bn = tid & 127;           // B-col within tile, 0..127
    const int bc0 = tid >> 7;           // B chunks {bc0, bc0+2}

    for (int k0 = 0; k0 < K; k0 += 32) {
        // stage A tile (row-major, k-contiguous) with bf16 cast
#pragma unroll
        for (int i = 0; i < 2; ++i) {
            const int kk = (ac0 + i) << 3;
            bf16x8 v = {};
            const int gm = m0 + ar;
            if (gm < M) {
                const float* p = A + (size_t)gm * K + k0 + kk;
                const float4 f0 = *(const float4*)p;
                const float4 f1 = *(const float4*)(p + 4);
                v[0] = (__bf16)f0.x; v[1] = (__bf16)f0.y;
                v[2] = (__bf16)f0.z; v[3] = (__bf16)f0.w;
                v[4] = (__bf16)f1.x; v[5] = (__bf16)f1.y;
                v[6] = (__bf16)f1.z; v[7] = (__bf16)f1.w;
            }
            *(bf16x8*)&As[ar * 40 + kk] = v;
        }
        // stage B tile transposed: Bs[n][k], per-lane k-column gather
#pragma unroll
        for (int i = 0; i < 2; ++i) {
            const int kk = (bc0 + (i << 1)) << 3;
            const float* p = B + (size_t)(k0 + kk) * N + n0 + bn;
            bf16x8 v;
#pragma unroll
            for (int j = 0; j < 8; ++j) v[j] = (__bf16)p[(size_t)j * N];
            *(bf16x8*)&Bs[bn * 40 + kk] = v;
        }
        __syncthreads();
        bf16x8 af[4], bfr[4];
#pragma unroll
        for (int t = 0; t < 4; ++t) {
            af[t]  = *(const bf16x8*)&As[(wm + (t << 4) + mr) * 40 + (q << 3)];
            bfr[t] = *(const bf16x8*)&Bs[(wn + (t << 4) + mr) * 40 + (q << 3)];
        }
#pragma unroll
        for (int tm = 0; tm < 4; ++tm)
#pragma unroll
            for (int tn = 0; tn < 4; ++tn)
                acc[tm][tn] = __builtin_amdgcn_mfma_f32_16x16x32_bf16(
                    af[tm], bfr[tn], acc[tm][tn], 0, 0, 0);
        __syncthreads();
    }

    const bool hb = bias != nullptr;
    const bool hr = residual != nullptr;
#pragma unroll
    for (int tm = 0; tm < 4; ++tm) {
#pragma unroll
        for (int r = 0; r < 4; ++r) {
            const int row = m0 + wm + (tm << 4) + (q << 2) + r;
            if (row < M) {
#pragma unroll
                for (int tn = 0; tn < 4; ++tn) {
                    const int col = n0 + wn + (tn << 4) + mr;
                    float val = acc[tm][tn][r];
                    if (hb) val += bias[col];
                    if (act) val = 0.5f * val * (1.0f + erff(val * 0.70710678118654752f));
                    if (hr) val += residual[(size_t)row * N + col];
                    C[(size_t)row * N + col] = val;
                }
            }
        }
    }
}

// ---- convert full input fp16 caches to f32 output regions ----
__global__ __launch_bounds__(256) void cache_convert_kernel(
    const __half2* __restrict__ kin, const __half2* __restrict__ vin,
    float2* __restrict__ kout, float2* __restrict__ vout, int n2)
{
    int i = blockIdx.x * 256 + threadIdx.x;
    const int stride = gridDim.x * 256;
    for (; i < n2; i += stride) {
        kout[i] = __half22float2(kin[i]);
        vout[i] = __half22float2(vin[i]);
    }
}

// ---- split qkv row, RoPE q/k, fp16-round k/v into cache (stored f32) ----
__global__ __launch_bounds__(256) void rope_store_kernel(
    const float* __restrict__ qkv, float* __restrict__ q_buf,
    float* __restrict__ k_out, float* __restrict__ v_out,
    const int* __restrict__ steps, int layer)
{
    const int l = blockIdx.x, tid = threadIdx.x;
    const int offset = steps[layer];
    const int pos = offset + l;
    const float t = (float)pos;
    const float* base = qkv + (size_t)l * 3 * DM;
    for (int p = tid; p < NH * (DH / 2); p += 256) {
        const int h = p >> 5, j = p & 31;
        const float freq = powf(10000.0f, -(float)j / 32.0f);
        float sn, cs;
        sincosf(t * freq, &sn, &cs);
        const int e = h * DH + 2 * j;
        const float q1 = base[e], q2 = base[e + 1];
        q_buf[(size_t)l * DM + e]     = q1 * cs - q2 * sn;
        q_buf[(size_t)l * DM + e + 1] = q1 * sn + q2 * cs;
        const float k1 = base[DM + e], k2 = base[DM + e + 1];
        const size_t co = (size_t)pos * DM + e;
        k_out[co]     = __half2float(__float2half(k1 * cs - k2 * sn));
        k_out[co + 1] = __half2float(__float2half(k1 * sn + k2 * cs));
    }
    for (int e = tid; e < DM; e += 256) {
        v_out[(size_t)pos * DM + e] = __half2float(__float2half(base[2 * DM + e]));
    }
}

// ---- causal attention, one wave per (query l, head h), online softmax ----
__global__ __launch_bounds__(64) void attn_kernel(
    const float* __restrict__ q_buf, const float* __restrict__ kc,
    const float* __restrict__ vc, float* __restrict__ attn_out,
    const int* __restrict__ steps, int layer)
{
    const int l = blockIdx.x, h = blockIdx.y, lane = threadIdx.x;
    const int qpos = steps[layer] + l;
    const float qv = q_buf[(size_t)l * DM + h * DH + lane];
    float m = -INFINITY, lsum = 0.0f, acc = 0.0f;
    for (int s = 0; s <= qpos; ++s) {
        const size_t idx = (size_t)s * DM + h * DH + lane;
        float p = qv * kc[idx];
        p = wave_sum(p);
        const float score = p * 0.125f;  // 1/sqrt(64)
        const float mn = fmaxf(m, score);
        const float corr = __expf(m - mn);
        const float wgt = __expf(score - mn);
        lsum = lsum * corr + wgt;
        acc = acc * corr + wgt * vc[idx];
        m = mn;
    }
    attn_out[(size_t)l * DM + h * DH + lane] = acc / lsum;
}

// ---- final LN of last row + eos logit + new_steps ----
__global__ __launch_bounds__(256) void final_kernel(
    const float* __restrict__ x, const float* __restrict__ w,
    const float* __restrict__ b, const float* __restrict__ W_eos,
    const float* __restrict__ b_eos, const int* __restrict__ steps,
    float* __restrict__ out, size_t steps_off)
{
    const int tid = threadIdx.x;
    const float4 v = *(const float4*)(x + (size_t)(LSEQ - 1) * DM + tid * 4);
    float s = v.x + v.y + v.z + v.w;
    float ss = v.x * v.x + v.y * v.y + v.z * v.z + v.w * v.w;
    s = wave_sum(s); ss = wave_sum(ss);
    __shared__ float ls[4], lss[4], ds[4];
    const int wid = tid >> 6;
    if ((tid & 63) == 0) { ls[wid] = s; lss[wid] = ss; }
    __syncthreads();
    const float mu = (ls[0] + ls[1] + ls[2] + ls[3]) * (1.0f / DM);
    const float var = (lss[0] + lss[1] + lss[2] + lss[3]) * (1.0f / DM) - mu * mu;
    const float rstd = rsqrtf(var + 1e-5f);
    const float4 wv = *(const float4*)(w + tid * 4);
    const float4 bv = *(const float4*)(b + tid * 4);
    float4 o;
    o.x = (v.x - mu) * rstd * wv.x + bv.x;
    o.y = (v.y - mu) * rstd * wv.y + bv.y;
    o.z = (v.z - mu) * rstd * wv.z + bv.z;
    o.w = (v.w - mu) * rstd * wv.w + bv.w;
    *(float4*)(out + tid * 4) = o;
    const float4 we = *(const float4*)(W_eos + tid * 4);
    float pd = o.x * we.x + o.y * we.y + o.z * we.z + o.w * we.w;
    pd = wave_sum(pd);
    if ((tid & 63) == 0) ds[wid] = pd;
    __syncthreads();
    if (tid == 0) out[DM] = ds[0] + ds[1] + ds[2] + ds[3] + b_eos[0];
    if (tid < NUM_LAYERS) out[steps_off + tid] = (float)(steps[tid] + LSEQ);
}

extern "C" void kernel_launch(void* const* d_in, const int* in_sizes, int n_in,
                              void* d_out, int out_size, void* d_ws, size_t ws_size,
                              hipStream_t stream)
{
    (void)in_sizes; (void)n_in; (void)out_size; (void)ws_size;
    const float* sequence = (const float*)d_in[0];
    const float* text     = (const float*)d_in[1];
    const __half* k_caches = (const __half*)d_in[2];
    const __half* v_caches = (const __half*)d_in[3];
    const int* steps      = (const int*)d_in[4];
    const float* bos      = (const float*)d_in[5];
    const float* W_in     = (const float*)d_in[6];
    const float* b_in     = (const float*)d_in[7];
    const float* ln1_w    = (const float*)d_in[8];
    const float* ln1_b    = (const float*)d_in[9];
    const float* Wqkv     = (const float*)d_in[10];
    const float* Wo       = (const float*)d_in[11];
    const float* ln2_w    = (const float*)d_in[12];
    const float* ln2_b    = (const float*)d_in[13];
    const float* W1       = (const float*)d_in[14];
    const float* b1       = (const float*)d_in[15];
    const float* W2       = (const float*)d_in[16];
    const float* b2       = (const float*)d_in[17];
    const float* outn_w   = (const float*)d_in[18];
    const float* outn_b   = (const float*)d_in[19];
    const float* W_eos    = (const float*)d_in[20];
    const float* b_eos    = (const float*)d_in[21];

    float* out = (float*)d_out;
    const size_t cacheN = (size_t)NUM_LAYERS * MAX_SEQ * DM;  // 25165824
    float* out_k = out + 1025;
    float* out_v = out_k + cacheN;
    const size_t steps_off = 1025 + 2 * cacheN;

    float* ws = (float*)d_ws;
    float* x        = ws;                            // 544*1024
    float* h        = x + (size_t)LSEQ * DM;         // 544*1024
    float* q_buf    = h + (size_t)LSEQ * DM;         // 544*1024
    float* attn_out = q_buf + (size_t)LSEQ * DM;     // 544*1024
    float* big      = attn_out + (size_t)LSEQ * DM;  // 544*4096 (qkv / ff1)

    cache_convert_kernel<<<2048, 256, 0, stream>>>(
        (const __half2*)k_caches, (const __half2*)v_caches,
        (float2*)out_k, (float2*)out_v, (int)(cacheN / 2));
    build_x_kernel<<<LSEQ, 256, 0, stream>>>(text, sequence, bos, W_in, b_in, x);

    for (int i = 0; i < NUM_LAYERS; ++i) {
        float* kci = out_k + (size_t)i * MAX_SEQ * DM;
        float* vci = out_v + (size_t)i * MAX_SEQ * DM;
        ln_kernel<<<LSEQ, 256, 0, stream>>>(x, ln1_w + i * DM, ln1_b + i * DM, h);
        gemm_mfma_kernel<<<dim3(24, 5), 256, 0, stream>>>(
            h, Wqkv + (size_t)i * DM * 3 * DM, big, nullptr, nullptr, LSEQ, 3 * DM, DM, 0);
        rope_store_kernel<<<LSEQ, 256, 0, stream>>>(big, q_buf, kci, vci, steps, i);
        attn_kernel<<<dim3(LSEQ, NH), 64, 0, stream>>>(q_buf, kci, vci, attn_out, steps, i);
        gemm_mfma_kernel<<<dim3(8, 5), 256, 0, stream>>>(
            attn_out, Wo + (size_t)i * DM * DM, x, nullptr, x, LSEQ, DM, DM, 0);
        ln_kernel<<<LSEQ, 256, 0, stream>>>(x, ln2_w + i * DM, ln2_b + i * DM, h);
        gemm_mfma_kernel<<<dim3(32, 5), 256, 0, stream>>>(
            h, W1 + (size_t)i * DM * DFF, big, b1 + i * DFF, nullptr, LSEQ, DFF, DM, 1);
        gemm_mfma_kernel<<<dim3(8, 5), 256, 0, stream>>>(
            big, W2 + (size_t)i * DFF * DM, x, b2 + i * DM, x, LSEQ, DM, DFF, 0);
    }
    final_kernel<<<1, 256, 0, stream>>>(x, outn_w, outn_b, W_eos, b_eos, steps, out, steps_off);
}

// Round 3
// 2677.544 us; speedup vs baseline: 1.9757x; 1.5480x over previous
//
#include <hip/hip_runtime.h>
#include <hip/hip_fp16.h>
#include <math.h>

#define NUM_LAYERS 6
#define DM 1024
#define NH 16
#define DH 64
#define MAX_SEQ 4096
#define DFF 4096
#define LSEQ 544
#define TTOK 512
#define LATENT 32

typedef __bf16 bf16x8 __attribute__((ext_vector_type(8)));
typedef float floatx4 __attribute__((ext_vector_type(4)));

static __device__ __forceinline__ float wave_sum(float v) {
#pragma unroll
    for (int off = 32; off > 0; off >>= 1) v += __shfl_xor(v, off, 64);
    return v;
}

// ---- build x: rows 0..511 copy text, rows 512..543 = seq @ W_in + b_in ----
__global__ __launch_bounds__(256) void build_x_kernel(
    const float* __restrict__ text, const float* __restrict__ seq,
    const float* __restrict__ bos, const float* __restrict__ W_in,
    const float* __restrict__ b_in, float* __restrict__ x)
{
    const int l = blockIdx.x, tid = threadIdx.x;
    if (l < TTOK) {
        const float4* src = (const float4*)(text + (size_t)l * DM);
        float4* dst = (float4*)(x + (size_t)l * DM);
        dst[tid] = src[tid];
    } else {
        __shared__ float s[LATENT];
        const int r = l - TTOK;
        if (tid < LATENT) {
            float v = seq[r * LATENT + tid];
            s[tid] = (v != v) ? bos[tid] : v;  // NaN -> bos_emb
        }
        __syncthreads();
        for (int c = tid; c < DM; c += 256) {
            float acc = b_in[c];
#pragma unroll
            for (int k = 0; k < LATENT; ++k) acc = fmaf(s[k], W_in[k * DM + c], acc);
            x[(size_t)l * DM + c] = acc;
        }
    }
}

// ---- layernorm over rows of [LSEQ, 1024] ----
__global__ __launch_bounds__(256) void ln_kernel(
    const float* __restrict__ in, const float* __restrict__ w,
    const float* __restrict__ b, float* __restrict__ out)
{
    const int l = blockIdx.x, tid = threadIdx.x;
    const float4 v = *(const float4*)(in + (size_t)l * DM + tid * 4);
    float s = v.x + v.y + v.z + v.w;
    float ss = v.x * v.x + v.y * v.y + v.z * v.z + v.w * v.w;
    s = wave_sum(s); ss = wave_sum(ss);
    __shared__ float ls[4], lss[4];
    const int wid = tid >> 6;
    if ((tid & 63) == 0) { ls[wid] = s; lss[wid] = ss; }
    __syncthreads();
    const float mu = (ls[0] + ls[1] + ls[2] + ls[3]) * (1.0f / DM);
    const float var = (lss[0] + lss[1] + lss[2] + lss[3]) * (1.0f / DM) - mu * mu;
    const float rstd = rsqrtf(var + 1e-5f);
    const float4 wv = *(const float4*)(w + tid * 4);
    const float4 bv = *(const float4*)(b + tid * 4);
    float4 o;
    o.x = (v.x - mu) * rstd * wv.x + bv.x;
    o.y = (v.y - mu) * rstd * wv.y + bv.y;
    o.z = (v.z - mu) * rstd * wv.z + bv.z;
    o.w = (v.w - mu) * rstd * wv.w + bv.w;
    *(float4*)(out + (size_t)l * DM + tid * 4) = o;
}

// ---- bf16 MFMA GEMM: C[M,N] = act(A[M,K]@B[K,N] + bias) + residual ----
// 128x128 tile, BK=32, 256 threads = 4 waves, each wave 64x64 via 4x4 MFMA
__global__ __launch_bounds__(256) void gemm_mfma_kernel(
    const float* __restrict__ A, const float* __restrict__ B,
    float* __restrict__ C, const float* __restrict__ bias,
    const float* __restrict__ residual, int M, int N, int K, int act)
{
    __shared__ __bf16 As[128 * 40];
    __shared__ __bf16 Bs[128 * 40];
    const int tid = threadIdx.x;
    const int m0 = blockIdx.y << 7, n0 = blockIdx.x << 7;
    const int w = tid >> 6, lane = tid & 63;
    const int wm = (w >> 1) << 6, wn = (w & 1) << 6;
    const int q = lane >> 4, mr = lane & 15;

    floatx4 acc[4][4] = {};

    const int ar = tid >> 1;
    const int ac0 = (tid & 1) << 1;
    const int bn = tid & 127;
    const int bc0 = tid >> 7;

    for (int k0 = 0; k0 < K; k0 += 32) {
#pragma unroll
        for (int i = 0; i < 2; ++i) {
            const int kk = (ac0 + i) << 3;
            bf16x8 v = {};
            const int gm = m0 + ar;
            if (gm < M) {
                const float* p = A + (size_t)gm * K + k0 + kk;
                const float4 f0 = *(const float4*)p;
                const float4 f1 = *(const float4*)(p + 4);
                v[0] = (__bf16)f0.x; v[1] = (__bf16)f0.y;
                v[2] = (__bf16)f0.z; v[3] = (__bf16)f0.w;
                v[4] = (__bf16)f1.x; v[5] = (__bf16)f1.y;
                v[6] = (__bf16)f1.z; v[7] = (__bf16)f1.w;
            }
            *(bf16x8*)&As[ar * 40 + kk] = v;
        }
#pragma unroll
        for (int i = 0; i < 2; ++i) {
            const int kk = (bc0 + (i << 1)) << 3;
            const float* p = B + (size_t)(k0 + kk) * N + n0 + bn;
            bf16x8 v;
#pragma unroll
            for (int j = 0; j < 8; ++j) v[j] = (__bf16)p[(size_t)j * N];
            *(bf16x8*)&Bs[bn * 40 + kk] = v;
        }
        __syncthreads();
        bf16x8 af[4], bfr[4];
#pragma unroll
        for (int t = 0; t < 4; ++t) {
            af[t]  = *(const bf16x8*)&As[(wm + (t << 4) + mr) * 40 + (q << 3)];
            bfr[t] = *(const bf16x8*)&Bs[(wn + (t << 4) + mr) * 40 + (q << 3)];
        }
#pragma unroll
        for (int tm = 0; tm < 4; ++tm)
#pragma unroll
            for (int tn = 0; tn < 4; ++tn)
                acc[tm][tn] = __builtin_amdgcn_mfma_f32_16x16x32_bf16(
                    af[tm], bfr[tn], acc[tm][tn], 0, 0, 0);
        __syncthreads();
    }

    const bool hb = bias != nullptr;
    const bool hr = residual != nullptr;
#pragma unroll
    for (int tm = 0; tm < 4; ++tm) {
#pragma unroll
        for (int r = 0; r < 4; ++r) {
            const int row = m0 + wm + (tm << 4) + (q << 2) + r;
            if (row < M) {
#pragma unroll
                for (int tn = 0; tn < 4; ++tn) {
                    const int col = n0 + wn + (tn << 4) + mr;
                    float val = acc[tm][tn][r];
                    if (hb) val += bias[col];
                    if (act) val = 0.5f * val * (1.0f + erff(val * 0.70710678118654752f));
                    if (hr) val += residual[(size_t)row * N + col];
                    C[(size_t)row * N + col] = val;
                }
            }
        }
    }
}

// ---- convert full input fp16 caches to f32 output regions ----
__global__ __launch_bounds__(256) void cache_convert_kernel(
    const __half2* __restrict__ kin, const __half2* __restrict__ vin,
    float2* __restrict__ kout, float2* __restrict__ vout, int n2)
{
    int i = blockIdx.x * 256 + threadIdx.x;
    const int stride = gridDim.x * 256;
    for (; i < n2; i += stride) {
        kout[i] = __half22float2(kin[i]);
        vout[i] = __half22float2(vin[i]);
    }
}

// ---- split qkv row, RoPE q/k, fp16-round k/v into cache (stored f32) ----
__global__ __launch_bounds__(256) void rope_store_kernel(
    const float* __restrict__ qkv, float* __restrict__ q_buf,
    float* __restrict__ k_out, float* __restrict__ v_out,
    const int* __restrict__ steps, int layer)
{
    const int l = blockIdx.x, tid = threadIdx.x;
    const int offset = steps[layer];
    const int pos = offset + l;
    const float t = (float)pos;
    const float* base = qkv + (size_t)l * 3 * DM;
    for (int p = tid; p < NH * (DH / 2); p += 256) {
        const int h = p >> 5, j = p & 31;
        const float freq = powf(10000.0f, -(float)j / 32.0f);
        float sn, cs;
        sincosf(t * freq, &sn, &cs);
        const int e = h * DH + 2 * j;
        const float q1 = base[e], q2 = base[e + 1];
        q_buf[(size_t)l * DM + e]     = q1 * cs - q2 * sn;
        q_buf[(size_t)l * DM + e + 1] = q1 * sn + q2 * cs;
        const float k1 = base[DM + e], k2 = base[DM + e + 1];
        const size_t co = (size_t)pos * DM + e;
        k_out[co]     = __half2float(__float2half(k1 * cs - k2 * sn));
        k_out[co + 1] = __half2float(__float2half(k1 * sn + k2 * cs));
    }
    for (int e = tid; e < DM; e += 256) {
        v_out[(size_t)pos * DM + e] = __half2float(__float2half(base[2 * DM + e]));
    }
}

// ---- flash attention: block = (64-query tile, head), 4 waves, MFMA ----
__global__ __launch_bounds__(256) void attn_flash_kernel(
    const float* __restrict__ q_buf, const float* __restrict__ kc,
    const float* __restrict__ vc, float* __restrict__ attn_out,
    const int* __restrict__ steps, int layer)
{
    __shared__ __bf16 Qs[64 * 72];
    __shared__ __bf16 Ks[64 * 72];
    __shared__ __bf16 Ps[64 * 72];
    __shared__ __bf16 Vs[64 * 72];
    const int tid = threadIdx.x;
    const int i0 = blockIdx.x << 6;
    const int h  = blockIdx.y;
    const int offset = steps[layer];
    const int w = tid >> 6, lane = tid & 63;
    const int q = lane >> 4, mr = lane & 15;

    // ---- stage Q tile (scaled by 1/sqrt(DH)), bf16, rows>=LSEQ zeroed ----
    {
        const int row = tid >> 2, dc = (tid & 3) << 4;
        bf16x8 v0 = {}, v1 = {};
        if (i0 + row < LSEQ) {
            const float* p = q_buf + (size_t)(i0 + row) * DM + h * DH + dc;
#pragma unroll
            for (int j = 0; j < 8; ++j) v0[j] = (__bf16)(p[j] * 0.125f);
#pragma unroll
            for (int j = 0; j < 8; ++j) v1[j] = (__bf16)(p[8 + j] * 0.125f);
        }
        *(bf16x8*)&Qs[row * 72 + dc] = v0;
        *(bf16x8*)&Qs[row * 72 + dc + 8] = v1;
    }

    float m_i[4], l_i[4];
    floatx4 o_acc[4] = {};
#pragma unroll
    for (int r = 0; r < 4; ++r) { m_i[r] = -INFINITY; l_i[r] = 0.f; }

    const int qtop = i0 + 63 < LSEQ - 1 ? i0 + 63 : LSEQ - 1;
    const int qmax = offset + qtop;
    const int ntiles = (qmax >> 6) + 1;

    for (int t = 0; t < ntiles; ++t) {
        const int s0 = t << 6;
        // stage K tile (row-major, coalesced)
        {
            const int key = tid >> 2, dc = (tid & 3) << 4;
            const float* p = kc + (size_t)(s0 + key) * DM + h * DH + dc;
            bf16x8 v0, v1;
#pragma unroll
            for (int j = 0; j < 8; ++j) v0[j] = (__bf16)p[j];
#pragma unroll
            for (int j = 0; j < 8; ++j) v1[j] = (__bf16)p[8 + j];
            *(bf16x8*)&Ks[key * 72 + dc] = v0;
            *(bf16x8*)&Ks[key * 72 + dc + 8] = v1;
        }
        // stage V tile transposed: Vs[d][key]
        {
            const int d = tid & 63, c = tid >> 6;
            bf16x8 v0, v1;
#pragma unroll
            for (int j = 0; j < 8; ++j)
                v0[j] = (__bf16)vc[(size_t)(s0 + (c << 4) + j) * DM + h * DH + d];
#pragma unroll
            for (int j = 0; j < 8; ++j)
                v1[j] = (__bf16)vc[(size_t)(s0 + (c << 4) + 8 + j) * DM + h * DH + d];
            *(bf16x8*)&Vs[d * 72 + (c << 4)] = v0;
            *(bf16x8*)&Vs[d * 72 + (c << 4) + 8] = v1;
        }
        __syncthreads();  // B1: K/V staged

        // S = Q K^T : wave w -> rows 16w..16w+15, all 64 keys
        const bf16x8 a0 = *(const bf16x8*)&Qs[(16 * w + mr) * 72 + (q << 3)];
        const bf16x8 a1 = *(const bf16x8*)&Qs[(16 * w + mr) * 72 + 32 + (q << 3)];
        floatx4 s_acc[4];
#pragma unroll
        for (int c = 0; c < 4; ++c) {
            const bf16x8 b0 = *(const bf16x8*)&Ks[(16 * c + mr) * 72 + (q << 3)];
            const bf16x8 b1 = *(const bf16x8*)&Ks[(16 * c + mr) * 72 + 32 + (q << 3)];
            floatx4 z = {};
            z = __builtin_amdgcn_mfma_f32_16x16x32_bf16(a0, b0, z, 0, 0, 0);
            s_acc[c] = __builtin_amdgcn_mfma_f32_16x16x32_bf16(a1, b1, z, 0, 0, 0);
        }

        // causal mask + online softmax (row stats replicated in 16-lane groups)
        float alpha[4];
#pragma unroll
        for (int r = 0; r < 4; ++r) {
            const int qglob = i0 + 16 * w + 4 * q + r;
            const int klim = offset + qglob;
            float rmax = -INFINITY;
#pragma unroll
            for (int c = 0; c < 4; ++c) {
                if (s0 + 16 * c + mr > klim) s_acc[c][r] = -INFINITY;
                rmax = fmaxf(rmax, s_acc[c][r]);
            }
#pragma unroll
            for (int o2 = 1; o2 < 16; o2 <<= 1)
                rmax = fmaxf(rmax, __shfl_xor(rmax, o2, 64));
            const float mn = fmaxf(m_i[r], rmax);
            alpha[r] = __expf(m_i[r] - mn);
            m_i[r] = mn;
            float rsum = 0.f;
#pragma unroll
            for (int c = 0; c < 4; ++c) {
                const float pv = __expf(s_acc[c][r] - mn);
                s_acc[c][r] = pv;
                rsum += pv;
            }
#pragma unroll
            for (int o2 = 1; o2 < 16; o2 <<= 1)
                rsum += __shfl_xor(rsum, o2, 64);
            l_i[r] = l_i[r] * alpha[r] + rsum;
        }

        // write P (C-layout -> LDS row-major)
#pragma unroll
        for (int c = 0; c < 4; ++c)
#pragma unroll
            for (int r = 0; r < 4; ++r)
                Ps[(16 * w + 4 * q + r) * 72 + 16 * c + mr] = (__bf16)s_acc[c][r];
        __syncthreads();  // B2: P visible

        // rescale O accumulator
#pragma unroll
        for (int c2 = 0; c2 < 4; ++c2)
#pragma unroll
            for (int r = 0; r < 4; ++r)
                o_acc[c2][r] *= alpha[r];

        // O += P V
        const bf16x8 p0 = *(const bf16x8*)&Ps[(16 * w + mr) * 72 + (q << 3)];
        const bf16x8 p1 = *(const bf16x8*)&Ps[(16 * w + mr) * 72 + 32 + (q << 3)];
#pragma unroll
        for (int c2 = 0; c2 < 4; ++c2) {
            const bf16x8 v0 = *(const bf16x8*)&Vs[(16 * c2 + mr) * 72 + (q << 3)];
            const bf16x8 v1 = *(const bf16x8*)&Vs[(16 * c2 + mr) * 72 + 32 + (q << 3)];
            o_acc[c2] = __builtin_amdgcn_mfma_f32_16x16x32_bf16(p0, v0, o_acc[c2], 0, 0, 0);
            o_acc[c2] = __builtin_amdgcn_mfma_f32_16x16x32_bf16(p1, v1, o_acc[c2], 0, 0, 0);
        }
        __syncthreads();  // B3: safe to overwrite K/V/P next iter
    }

    // epilogue: normalize and store
#pragma unroll
    for (int r = 0; r < 4; ++r) {
        const int row = i0 + 16 * w + 4 * q + r;
        if (row < LSEQ) {
            const float inv = 1.0f / l_i[r];
#pragma unroll
            for (int c2 = 0; c2 < 4; ++c2)
                attn_out[(size_t)row * DM + h * DH + 16 * c2 + mr] = o_acc[c2][r] * inv;
        }
    }
}

// ---- final LN of last row + eos logit + new_steps ----
__global__ __launch_bounds__(256) void final_kernel(
    const float* __restrict__ x, const float* __restrict__ w,
    const float* __restrict__ b, const float* __restrict__ W_eos,
    const float* __restrict__ b_eos, const int* __restrict__ steps,
    float* __restrict__ out, size_t steps_off)
{
    const int tid = threadIdx.x;
    const float4 v = *(const float4*)(x + (size_t)(LSEQ - 1) * DM + tid * 4);
    float s = v.x + v.y + v.z + v.w;
    float ss = v.x * v.x + v.y * v.y + v.z * v.z + v.w * v.w;
    s = wave_sum(s); ss = wave_sum(ss);
    __shared__ float ls[4], lss[4], ds[4];
    const int wid = tid >> 6;
    if ((tid & 63) == 0) { ls[wid] = s; lss[wid] = ss; }
    __syncthreads();
    const float mu = (ls[0] + ls[1] + ls[2] + ls[3]) * (1.0f / DM);
    const float var = (lss[0] + lss[1] + lss[2] + lss[3]) * (1.0f / DM) - mu * mu;
    const float rstd = rsqrtf(var + 1e-5f);
    const float4 wv = *(const float4*)(w + tid * 4);
    const float4 bv = *(const float4*)(b + tid * 4);
    float4 o;
    o.x = (v.x - mu) * rstd * wv.x + bv.x;
    o.y = (v.y - mu) * rstd * wv.y + bv.y;
    o.z = (v.z - mu) * rstd * wv.z + bv.z;
    o.w = (v.w - mu) * rstd * wv.w + bv.w;
    *(float4*)(out + tid * 4) = o;
    const float4 we = *(const float4*)(W_eos + tid * 4);
    float pd = o.x * we.x + o.y * we.y + o.z * we.z + o.w * we.w;
    pd = wave_sum(pd);
    if ((tid & 63) == 0) ds[wid] = pd;
    __syncthreads();
    if (tid == 0) out[DM] = ds[0] + ds[1] + ds[2] + ds[3] + b_eos[0];
    if (tid < NUM_LAYERS) out[steps_off + tid] = (float)(steps[tid] + LSEQ);
}

extern "C" void kernel_launch(void* const* d_in, const int* in_sizes, int n_in,
                              void* d_out, int out_size, void* d_ws, size_t ws_size,
                              hipStream_t stream)
{
    (void)in_sizes; (void)n_in; (void)out_size; (void)ws_size;
    const float* sequence = (const float*)d_in[0];
    const float* text     = (const float*)d_in[1];
    const __half* k_caches = (const __half*)d_in[2];
    const __half* v_caches = (const __half*)d_in[3];
    const int* steps      = (const int*)d_in[4];
    const float* bos      = (const float*)d_in[5];
    const float* W_in     = (const float*)d_in[6];
    const float* b_in     = (const float*)d_in[7];
    const float* ln1_w    = (const float*)d_in[8];
    const float* ln1_b    = (const float*)d_in[9];
    const float* Wqkv     = (const float*)d_in[10];
    const float* Wo       = (const float*)d_in[11];
    const float* ln2_w    = (const float*)d_in[12];
    const float* ln2_b    = (const float*)d_in[13];
    const float* W1       = (const float*)d_in[14];
    const float* b1       = (const float*)d_in[15];
    const float* W2       = (const float*)d_in[16];
    const float* b2       = (const float*)d_in[17];
    const float* outn_w   = (const float*)d_in[18];
    const float* outn_b   = (const float*)d_in[19];
    const float* W_eos    = (const float*)d_in[20];
    const float* b_eos    = (const float*)d_in[21];

    float* out = (float*)d_out;
    const size_t cacheN = (size_t)NUM_LAYERS * MAX_SEQ * DM;  // 25165824
    float* out_k = out + 1025;
    float* out_v = out_k + cacheN;
    const size_t steps_off = 1025 + 2 * cacheN;

    float* ws = (float*)d_ws;
    float* x        = ws;
    float* h        = x + (size_t)LSEQ * DM;
    float* q_buf    = h + (size_t)LSEQ * DM;
    float* attn_out = q_buf + (size_t)LSEQ * DM;
    float* big      = attn_out + (size_t)LSEQ * DM;

    cache_convert_kernel<<<2048, 256, 0, stream>>>(
        (const __half2*)k_caches, (const __half2*)v_caches,
        (float2*)out_k, (float2*)out_v, (int)(cacheN / 2));
    build_x_kernel<<<LSEQ, 256, 0, stream>>>(text, sequence, bos, W_in, b_in, x);

    for (int i = 0; i < NUM_LAYERS; ++i) {
        float* kci = out_k + (size_t)i * MAX_SEQ * DM;
        float* vci = out_v + (size_t)i * MAX_SEQ * DM;
        ln_kernel<<<LSEQ, 256, 0, stream>>>(x, ln1_w + i * DM, ln1_b + i * DM, h);
        gemm_mfma_kernel<<<dim3(24, 5), 256, 0, stream>>>(
            h, Wqkv + (size_t)i * DM * 3 * DM, big, nullptr, nullptr, LSEQ, 3 * DM, DM, 0);
        rope_store_kernel<<<LSEQ, 256, 0, stream>>>(big, q_buf, kci, vci, steps, i);
        attn_flash_kernel<<<dim3(9, NH), 256, 0, stream>>>(q_buf, kci, vci, attn_out, steps, i);
        gemm_mfma_kernel<<<dim3(8, 5), 256, 0, stream>>>(
            attn_out, Wo + (size_t)i * DM * DM, x, nullptr, x, LSEQ, DM, DM, 0);
        ln_kernel<<<LSEQ, 256, 0, stream>>>(x, ln2_w + i * DM, ln2_b + i * DM, h);
        gemm_mfma_kernel<<<dim3(32, 5), 256, 0, stream>>>(
            h, W1 + (size_t)i * DM * DFF, big, b1 + i * DFF, nullptr, LSEQ, DFF, DM, 1);
        gemm_mfma_kernel<<<dim3(8, 5), 256, 0, stream>>>(
            big, W2 + (size_t)i * DFF * DM, x, b2 + i * DM, x, LSEQ, DM, DFF, 0);
    }
    final_kernel<<<1, 256, 0, stream>>>(x, outn_w, outn_b, W_eos, b_eos, steps, out, steps_off);
}

// Round 4
// 1320.274 us; speedup vs baseline: 4.0068x; 2.0280x over previous
//
#include <hip/hip_runtime.h>
#include <hip/hip_fp16.h>
#include <math.h>

#define NUM_LAYERS 6
#define DM 1024
#define NH 16
#define DH 64
#define MAX_SEQ 4096
#define DFF 4096
#define LSEQ 544
#define TTOK 512
#define LATENT 32

typedef __bf16 bf16x8 __attribute__((ext_vector_type(8)));
typedef float floatx4 __attribute__((ext_vector_type(4)));

static __device__ __forceinline__ float wave_sum(float v) {
#pragma unroll
    for (int off = 32; off > 0; off >>= 1) v += __shfl_xor(v, off, 64);
    return v;
}

// ---- build x ----
__global__ __launch_bounds__(256) void build_x_kernel(
    const float* __restrict__ text, const float* __restrict__ seq,
    const float* __restrict__ bos, const float* __restrict__ W_in,
    const float* __restrict__ b_in, float* __restrict__ x)
{
    const int l = blockIdx.x, tid = threadIdx.x;
    if (l < TTOK) {
        const float4* src = (const float4*)(text + (size_t)l * DM);
        float4* dst = (float4*)(x + (size_t)l * DM);
        dst[tid] = src[tid];
    } else {
        __shared__ float s[LATENT];
        const int r = l - TTOK;
        if (tid < LATENT) {
            float v = seq[r * LATENT + tid];
            s[tid] = (v != v) ? bos[tid] : v;
        }
        __syncthreads();
        for (int c = tid; c < DM; c += 256) {
            float acc = b_in[c];
#pragma unroll
            for (int k = 0; k < LATENT; ++k) acc = fmaf(s[k], W_in[k * DM + c], acc);
            x[(size_t)l * DM + c] = acc;
        }
    }
}

// ---- layernorm ----
__global__ __launch_bounds__(256) void ln_kernel(
    const float* __restrict__ in, const float* __restrict__ w,
    const float* __restrict__ b, float* __restrict__ out)
{
    const int l = blockIdx.x, tid = threadIdx.x;
    const float4 v = *(const float4*)(in + (size_t)l * DM + tid * 4);
    float s = v.x + v.y + v.z + v.w;
    float ss = v.x * v.x + v.y * v.y + v.z * v.z + v.w * v.w;
    s = wave_sum(s); ss = wave_sum(ss);
    __shared__ float ls[4], lss[4];
    const int wid = tid >> 6;
    if ((tid & 63) == 0) { ls[wid] = s; lss[wid] = ss; }
    __syncthreads();
    const float mu = (ls[0] + ls[1] + ls[2] + ls[3]) * (1.0f / DM);
    const float var = (lss[0] + lss[1] + lss[2] + lss[3]) * (1.0f / DM) - mu * mu;
    const float rstd = rsqrtf(var + 1e-5f);
    const float4 wv = *(const float4*)(w + tid * 4);
    const float4 bv = *(const float4*)(b + tid * 4);
    float4 o;
    o.x = (v.x - mu) * rstd * wv.x + bv.x;
    o.y = (v.y - mu) * rstd * wv.y + bv.y;
    o.z = (v.z - mu) * rstd * wv.z + bv.z;
    o.w = (v.w - mu) * rstd * wv.w + bv.w;
    *(float4*)(out + (size_t)l * DM + tid * 4) = o;
}

// ---- transpose+cast: in f32 [K][N] (layer-strided) -> out bf16 [N][K] ----
__global__ __launch_bounds__(256) void transpose_cast_kernel(
    const float* __restrict__ in, __bf16* __restrict__ out, int K, int N)
{
    __shared__ float T[32][33];
    const size_t zoff = (size_t)blockIdx.z * K * N;
    in += zoff; out += zoff;
    const int n0 = blockIdx.x << 5, k0 = blockIdx.y << 5;
    const int tx = threadIdx.x & 31, ty = threadIdx.x >> 5;
#pragma unroll
    for (int i = 0; i < 4; ++i)
        T[ty + 8 * i][tx] = in[(size_t)(k0 + ty + 8 * i) * N + n0 + tx];
    __syncthreads();
#pragma unroll
    for (int i = 0; i < 4; ++i)
        out[(size_t)(n0 + ty + 8 * i) * K + k0 + tx] = (__bf16)T[tx][ty + 8 * i];
}

// ---- bf16 MFMA GEMM, B pre-transposed bf16 [N][K] ----
// 64x128 tile, BK=64, 4 waves, register->LDS prefetch pipeline.
// split-K via blockIdx.z (ksl elems per slice); atomic_out accumulates into C.
__global__ __launch_bounds__(256) void gemm_bt_kernel(
    const float* __restrict__ A, const __bf16* __restrict__ Bt,
    float* __restrict__ C, const float* __restrict__ bias,
    const float* __restrict__ residual,
    int M, int N, int K, int ksl, int act, int atomic_out)
{
    __shared__ __bf16 As[64 * 72];
    __shared__ __bf16 Bs[128 * 72];
    const int tid = threadIdx.x;
    const int m0 = blockIdx.y << 6, n0 = blockIdx.x << 7;
    const int kb = blockIdx.z * ksl, ke = kb + ksl;
    const int w = tid >> 6, lane = tid & 63;
    const int wm = (w >> 1) << 5, wn = (w & 1) << 6;
    const int q = lane >> 4, mr = lane & 15;

    const int arow = tid >> 2, akc = (tid & 3) << 4;   // A: row, 16-float chunk
    const int brow = tid >> 1, bkc = (tid & 1) << 5;   // B: row, 32-bf16 chunk

    floatx4 acc[2][4] = {};
    float4 a4[4];
    bf16x8 b8[4];

    // prologue load
    {
        const int gm = m0 + arow;
        if (gm < M) {
            const float* p = A + (size_t)gm * K + kb + akc;
#pragma unroll
            for (int j = 0; j < 4; ++j) a4[j] = *(const float4*)(p + 4 * j);
        } else {
#pragma unroll
            for (int j = 0; j < 4; ++j) a4[j] = make_float4(0.f, 0.f, 0.f, 0.f);
        }
        const __bf16* p = Bt + (size_t)(n0 + brow) * K + kb + bkc;
#pragma unroll
        for (int j = 0; j < 4; ++j) b8[j] = *(const bf16x8*)(p + 8 * j);
    }

    for (int k0 = kb; k0 < ke; k0 += 64) {
        __syncthreads();  // previous compute done; LDS reusable
        bf16x8 av0, av1;
#pragma unroll
        for (int j = 0; j < 4; ++j) {
            av0[2 * j + 0] = (__bf16)((j < 2) ? ((const float*)&a4[j])[0] : 0.f);
        }
        // pack a4[0..1] -> av0, a4[2..3] -> av1
        av0[0] = (__bf16)a4[0].x; av0[1] = (__bf16)a4[0].y;
        av0[2] = (__bf16)a4[0].z; av0[3] = (__bf16)a4[0].w;
        av0[4] = (__bf16)a4[1].x; av0[5] = (__bf16)a4[1].y;
        av0[6] = (__bf16)a4[1].z; av0[7] = (__bf16)a4[1].w;
        av1[0] = (__bf16)a4[2].x; av1[1] = (__bf16)a4[2].y;
        av1[2] = (__bf16)a4[2].z; av1[3] = (__bf16)a4[2].w;
        av1[4] = (__bf16)a4[3].x; av1[5] = (__bf16)a4[3].y;
        av1[6] = (__bf16)a4[3].z; av1[7] = (__bf16)a4[3].w;
        *(bf16x8*)&As[arow * 72 + akc] = av0;
        *(bf16x8*)&As[arow * 72 + akc + 8] = av1;
#pragma unroll
        for (int j = 0; j < 4; ++j)
            *(bf16x8*)&Bs[brow * 72 + bkc + 8 * j] = b8[j];
        __syncthreads();  // LDS visible

        // prefetch next iteration (latency hidden behind MFMA below)
        if (k0 + 64 < ke) {
            const int gm = m0 + arow;
            if (gm < M) {
                const float* p = A + (size_t)gm * K + k0 + 64 + akc;
#pragma unroll
                for (int j = 0; j < 4; ++j) a4[j] = *(const float4*)(p + 4 * j);
            }
            const __bf16* p = Bt + (size_t)(n0 + brow) * K + k0 + 64 + bkc;
#pragma unroll
            for (int j = 0; j < 4; ++j) b8[j] = *(const bf16x8*)(p + 8 * j);
        }

#pragma unroll
        for (int s = 0; s < 2; ++s) {
            const bf16x8 fa0 = *(const bf16x8*)&As[(wm + mr) * 72 + (s << 5) + (q << 3)];
            const bf16x8 fa1 = *(const bf16x8*)&As[(wm + 16 + mr) * 72 + (s << 5) + (q << 3)];
            bf16x8 fb[4];
#pragma unroll
            for (int nt = 0; nt < 4; ++nt)
                fb[nt] = *(const bf16x8*)&Bs[(wn + (nt << 4) + mr) * 72 + (s << 5) + (q << 3)];
#pragma unroll
            for (int nt = 0; nt < 4; ++nt) {
                acc[0][nt] = __builtin_amdgcn_mfma_f32_16x16x32_bf16(fa0, fb[nt], acc[0][nt], 0, 0, 0);
                acc[1][nt] = __builtin_amdgcn_mfma_f32_16x16x32_bf16(fa1, fb[nt], acc[1][nt], 0, 0, 0);
            }
        }
    }

    const bool hb = (bias != nullptr) && (kb == 0);
    const bool hr = residual != nullptr;
#pragma unroll
    for (int mt = 0; mt < 2; ++mt) {
#pragma unroll
        for (int r = 0; r < 4; ++r) {
            const int row = m0 + wm + (mt << 4) + (q << 2) + r;
            if (row < M) {
#pragma unroll
                for (int nt = 0; nt < 4; ++nt) {
                    const int col = n0 + wn + (nt << 4) + mr;
                    float val = acc[mt][nt][r];
                    if (hb) val += bias[col];
                    if (act) val = 0.5f * val * (1.0f + erff(val * 0.70710678118654752f));
                    if (atomic_out) {
                        atomicAdd(&C[(size_t)row * N + col], val);
                    } else {
                        if (hr) val += residual[(size_t)row * N + col];
                        C[(size_t)row * N + col] = val;
                    }
                }
            }
        }
    }
}

// ---- legacy fp32-B GEMM (fallback when ws too small) ----
__global__ __launch_bounds__(256) void gemm_mfma_kernel(
    const float* __restrict__ A, const float* __restrict__ B,
    float* __restrict__ C, const float* __restrict__ bias,
    const float* __restrict__ residual, int M, int N, int K, int act)
{
    __shared__ __bf16 As[128 * 40];
    __shared__ __bf16 Bs[128 * 40];
    const int tid = threadIdx.x;
    const int m0 = blockIdx.y << 7, n0 = blockIdx.x << 7;
    const int w = tid >> 6, lane = tid & 63;
    const int wm = (w >> 1) << 6, wn = (w & 1) << 6;
    const int q = lane >> 4, mr = lane & 15;
    floatx4 acc[4][4] = {};
    const int ar = tid >> 1;
    const int ac0 = (tid & 1) << 1;
    const int bn = tid & 127;
    const int bc0 = tid >> 7;
    for (int k0 = 0; k0 < K; k0 += 32) {
#pragma unroll
        for (int i = 0; i < 2; ++i) {
            const int kk = (ac0 + i) << 3;
            bf16x8 v = {};
            const int gm = m0 + ar;
            if (gm < M) {
                const float* p = A + (size_t)gm * K + k0 + kk;
                const float4 f0 = *(const float4*)p;
                const float4 f1 = *(const float4*)(p + 4);
                v[0] = (__bf16)f0.x; v[1] = (__bf16)f0.y;
                v[2] = (__bf16)f0.z; v[3] = (__bf16)f0.w;
                v[4] = (__bf16)f1.x; v[5] = (__bf16)f1.y;
                v[6] = (__bf16)f1.z; v[7] = (__bf16)f1.w;
            }
            *(bf16x8*)&As[ar * 40 + kk] = v;
        }
#pragma unroll
        for (int i = 0; i < 2; ++i) {
            const int kk = (bc0 + (i << 1)) << 3;
            const float* p = B + (size_t)(k0 + kk) * N + n0 + bn;
            bf16x8 v;
#pragma unroll
            for (int j = 0; j < 8; ++j) v[j] = (__bf16)p[(size_t)j * N];
            *(bf16x8*)&Bs[bn * 40 + kk] = v;
        }
        __syncthreads();
        bf16x8 af[4], bfr[4];
#pragma unroll
        for (int t = 0; t < 4; ++t) {
            af[t]  = *(const bf16x8*)&As[(wm + (t << 4) + mr) * 40 + (q << 3)];
            bfr[t] = *(const bf16x8*)&Bs[(wn + (t << 4) + mr) * 40 + (q << 3)];
        }
#pragma unroll
        for (int tm = 0; tm < 4; ++tm)
#pragma unroll
            for (int tn = 0; tn < 4; ++tn)
                acc[tm][tn] = __builtin_amdgcn_mfma_f32_16x16x32_bf16(
                    af[tm], bfr[tn], acc[tm][tn], 0, 0, 0);
        __syncthreads();
    }
    const bool hb = bias != nullptr;
    const bool hr = residual != nullptr;
#pragma unroll
    for (int tm = 0; tm < 4; ++tm) {
#pragma unroll
        for (int r = 0; r < 4; ++r) {
            const int row = m0 + wm + (tm << 4) + (q << 2) + r;
            if (row < M) {
#pragma unroll
                for (int tn = 0; tn < 4; ++tn) {
                    const int col = n0 + wn + (tn << 4) + mr;
                    float val = acc[tm][tn][r];
                    if (hb) val += bias[col];
                    if (act) val = 0.5f * val * (1.0f + erff(val * 0.70710678118654752f));
                    if (hr) val += residual[(size_t)row * N + col];
                    C[(size_t)row * N + col] = val;
                }
            }
        }
    }
}

// ---- fp16 caches -> f32 output, 16B loads ----
__global__ __launch_bounds__(256) void cache_convert_kernel(
    const uint4* __restrict__ kin, const uint4* __restrict__ vin,
    float4* __restrict__ kout, float4* __restrict__ vout, int n8)
{
    int i = blockIdx.x * 256 + threadIdx.x;
    const int stride = gridDim.x * 256;
    for (; i < n8; i += stride) {
        uint4 u = kin[i];
        const __half2* h = (const __half2*)&u;
        float2 f0 = __half22float2(h[0]), f1 = __half22float2(h[1]);
        float2 f2 = __half22float2(h[2]), f3 = __half22float2(h[3]);
        kout[2 * i]     = make_float4(f0.x, f0.y, f1.x, f1.y);
        kout[2 * i + 1] = make_float4(f2.x, f2.y, f3.x, f3.y);
        u = vin[i];
        f0 = __half22float2(h[0]); f1 = __half22float2(h[1]);
        f2 = __half22float2(h[2]); f3 = __half22float2(h[3]);
        vout[2 * i]     = make_float4(f0.x, f0.y, f1.x, f1.y);
        vout[2 * i + 1] = make_float4(f2.x, f2.y, f3.x, f3.y);
    }
}

// ---- RoPE + cache store ----
__global__ __launch_bounds__(256) void rope_store_kernel(
    const float* __restrict__ qkv, float* __restrict__ q_buf,
    float* __restrict__ k_out, float* __restrict__ v_out,
    const int* __restrict__ steps, int layer)
{
    const int l = blockIdx.x, tid = threadIdx.x;
    const int offset = steps[layer];
    const int pos = offset + l;
    const float t = (float)pos;
    const float* base = qkv + (size_t)l * 3 * DM;
    for (int p = tid; p < NH * (DH / 2); p += 256) {
        const int h = p >> 5, j = p & 31;
        const float freq = powf(10000.0f, -(float)j / 32.0f);
        float sn, cs;
        sincosf(t * freq, &sn, &cs);
        const int e = h * DH + 2 * j;
        const float q1 = base[e], q2 = base[e + 1];
        q_buf[(size_t)l * DM + e]     = q1 * cs - q2 * sn;
        q_buf[(size_t)l * DM + e + 1] = q1 * sn + q2 * cs;
        const float k1 = base[DM + e], k2 = base[DM + e + 1];
        const size_t co = (size_t)pos * DM + e;
        k_out[co]     = __half2float(__float2half(k1 * cs - k2 * sn));
        k_out[co + 1] = __half2float(__float2half(k1 * sn + k2 * cs));
    }
    for (int e = tid; e < DM; e += 256) {
        v_out[(size_t)pos * DM + e] = __half2float(__float2half(base[2 * DM + e]));
    }
}

// ---- flash attention ----
__global__ __launch_bounds__(256) void attn_flash_kernel(
    const float* __restrict__ q_buf, const float* __restrict__ kc,
    const float* __restrict__ vc, float* __restrict__ attn_out,
    const int* __restrict__ steps, int layer)
{
    __shared__ __bf16 Qs[64 * 72];
    __shared__ __bf16 Ks[64 * 72];
    __shared__ __bf16 Ps[64 * 72];
    __shared__ __bf16 Vs[64 * 72];
    const int tid = threadIdx.x;
    const int i0 = blockIdx.x << 6;
    const int h  = blockIdx.y;
    const int offset = steps[layer];
    const int w = tid >> 6, lane = tid & 63;
    const int q = lane >> 4, mr = lane & 15;

    {
        const int row = tid >> 2, dc = (tid & 3) << 4;
        bf16x8 v0 = {}, v1 = {};
        if (i0 + row < LSEQ) {
            const float* p = q_buf + (size_t)(i0 + row) * DM + h * DH + dc;
#pragma unroll
            for (int j = 0; j < 8; ++j) v0[j] = (__bf16)(p[j] * 0.125f);
#pragma unroll
            for (int j = 0; j < 8; ++j) v1[j] = (__bf16)(p[8 + j] * 0.125f);
        }
        *(bf16x8*)&Qs[row * 72 + dc] = v0;
        *(bf16x8*)&Qs[row * 72 + dc + 8] = v1;
    }

    float m_i[4], l_i[4];
    floatx4 o_acc[4] = {};
#pragma unroll
    for (int r = 0; r < 4; ++r) { m_i[r] = -INFINITY; l_i[r] = 0.f; }

    const int qtop = i0 + 63 < LSEQ - 1 ? i0 + 63 : LSEQ - 1;
    const int qmax = offset + qtop;
    const int ntiles = (qmax >> 6) + 1;

    for (int t = 0; t < ntiles; ++t) {
        const int s0 = t << 6;
        {
            const int key = tid >> 2, dc = (tid & 3) << 4;
            const float* p = kc + (size_t)(s0 + key) * DM + h * DH + dc;
            bf16x8 v0, v1;
#pragma unroll
            for (int j = 0; j < 8; ++j) v0[j] = (__bf16)p[j];
#pragma unroll
            for (int j = 0; j < 8; ++j) v1[j] = (__bf16)p[8 + j];
            *(bf16x8*)&Ks[key * 72 + dc] = v0;
            *(bf16x8*)&Ks[key * 72 + dc + 8] = v1;
        }
        {
            const int d = tid & 63, c = tid >> 6;
            bf16x8 v0, v1;
#pragma unroll
            for (int j = 0; j < 8; ++j)
                v0[j] = (__bf16)vc[(size_t)(s0 + (c << 4) + j) * DM + h * DH + d];
#pragma unroll
            for (int j = 0; j < 8; ++j)
                v1[j] = (__bf16)vc[(size_t)(s0 + (c << 4) + 8 + j) * DM + h * DH + d];
            *(bf16x8*)&Vs[d * 72 + (c << 4)] = v0;
            *(bf16x8*)&Vs[d * 72 + (c << 4) + 8] = v1;
        }
        __syncthreads();

        const bf16x8 a0 = *(const bf16x8*)&Qs[(16 * w + mr) * 72 + (q << 3)];
        const bf16x8 a1 = *(const bf16x8*)&Qs[(16 * w + mr) * 72 + 32 + (q << 3)];
        floatx4 s_acc[4];
#pragma unroll
        for (int c = 0; c < 4; ++c) {
            const bf16x8 b0 = *(const bf16x8*)&Ks[(16 * c + mr) * 72 + (q << 3)];
            const bf16x8 b1 = *(const bf16x8*)&Ks[(16 * c + mr) * 72 + 32 + (q << 3)];
            floatx4 z = {};
            z = __builtin_amdgcn_mfma_f32_16x16x32_bf16(a0, b0, z, 0, 0, 0);
            s_acc[c] = __builtin_amdgcn_mfma_f32_16x16x32_bf16(a1, b1, z, 0, 0, 0);
        }

        float alpha[4];
#pragma unroll
        for (int r = 0; r < 4; ++r) {
            const int qglob = i0 + 16 * w + 4 * q + r;
            const int klim = offset + qglob;
            float rmax = -INFINITY;
#pragma unroll
            for (int c = 0; c < 4; ++c) {
                if (s0 + 16 * c + mr > klim) s_acc[c][r] = -INFINITY;
                rmax = fmaxf(rmax, s_acc[c][r]);
            }
#pragma unroll
            for (int o2 = 1; o2 < 16; o2 <<= 1)
                rmax = fmaxf(rmax, __shfl_xor(rmax, o2, 64));
            const float mn = fmaxf(m_i[r], rmax);
            alpha[r] = __expf(m_i[r] - mn);
            m_i[r] = mn;
            float rsum = 0.f;
#pragma unroll
            for (int c = 0; c < 4; ++c) {
                const float pv = __expf(s_acc[c][r] - mn);
                s_acc[c][r] = pv;
                rsum += pv;
            }
#pragma unroll
            for (int o2 = 1; o2 < 16; o2 <<= 1)
                rsum += __shfl_xor(rsum, o2, 64);
            l_i[r] = l_i[r] * alpha[r] + rsum;
        }

#pragma unroll
        for (int c = 0; c < 4; ++c)
#pragma unroll
            for (int r = 0; r < 4; ++r)
                Ps[(16 * w + 4 * q + r) * 72 + 16 * c + mr] = (__bf16)s_acc[c][r];
        __syncthreads();

#pragma unroll
        for (int c2 = 0; c2 < 4; ++c2)
#pragma unroll
            for (int r = 0; r < 4; ++r)
                o_acc[c2][r] *= alpha[r];

        const bf16x8 p0 = *(const bf16x8*)&Ps[(16 * w + mr) * 72 + (q << 3)];
        const bf16x8 p1 = *(const bf16x8*)&Ps[(16 * w + mr) * 72 + 32 + (q << 3)];
#pragma unroll
        for (int c2 = 0; c2 < 4; ++c2) {
            const bf16x8 v0 = *(const bf16x8*)&Vs[(16 * c2 + mr) * 72 + (q << 3)];
            const bf16x8 v1 = *(const bf16x8*)&Vs[(16 * c2 + mr) * 72 + 32 + (q << 3)];
            o_acc[c2] = __builtin_amdgcn_mfma_f32_16x16x32_bf16(p0, v0, o_acc[c2], 0, 0, 0);
            o_acc[c2] = __builtin_amdgcn_mfma_f32_16x16x32_bf16(p1, v1, o_acc[c2], 0, 0, 0);
        }
        __syncthreads();
    }

#pragma unroll
    for (int r = 0; r < 4; ++r) {
        const int row = i0 + 16 * w + 4 * q + r;
        if (row < LSEQ) {
            const float inv = 1.0f / l_i[r];
#pragma unroll
            for (int c2 = 0; c2 < 4; ++c2)
                attn_out[(size_t)row * DM + h * DH + 16 * c2 + mr] = o_acc[c2][r] * inv;
        }
    }
}

// ---- final LN + eos + steps ----
__global__ __launch_bounds__(256) void final_kernel(
    const float* __restrict__ x, const float* __restrict__ w,
    const float* __restrict__ b, const float* __restrict__ W_eos,
    const float* __restrict__ b_eos, const int* __restrict__ steps,
    float* __restrict__ out, size_t steps_off)
{
    const int tid = threadIdx.x;
    const float4 v = *(const float4*)(x + (size_t)(LSEQ - 1) * DM + tid * 4);
    float s = v.x + v.y + v.z + v.w;
    float ss = v.x * v.x + v.y * v.y + v.z * v.z + v.w * v.w;
    s = wave_sum(s); ss = wave_sum(ss);
    __shared__ float ls[4], lss[4], ds[4];
    const int wid = tid >> 6;
    if ((tid & 63) == 0) { ls[wid] = s; lss[wid] = ss; }
    __syncthreads();
    const float mu = (ls[0] + ls[1] + ls[2] + ls[3]) * (1.0f / DM);
    const float var = (lss[0] + lss[1] + lss[2] + lss[3]) * (1.0f / DM) - mu * mu;
    const float rstd = rsqrtf(var + 1e-5f);
    const float4 wv = *(const float4*)(w + tid * 4);
    const float4 bv = *(const float4*)(b + tid * 4);
    float4 o;
    o.x = (v.x - mu) * rstd * wv.x + bv.x;
    o.y = (v.y - mu) * rstd * wv.y + bv.y;
    o.z = (v.z - mu) * rstd * wv.z + bv.z;
    o.w = (v.w - mu) * rstd * wv.w + bv.w;
    *(float4*)(out + tid * 4) = o;
    const float4 we = *(const float4*)(W_eos + tid * 4);
    float pd = o.x * we.x + o.y * we.y + o.z * we.z + o.w * we.w;
    pd = wave_sum(pd);
    if ((tid & 63) == 0) ds[wid] = pd;
    __syncthreads();
    if (tid == 0) out[DM] = ds[0] + ds[1] + ds[2] + ds[3] + b_eos[0];
    if (tid < NUM_LAYERS) out[steps_off + tid] = (float)(steps[tid] + LSEQ);
}

extern "C" void kernel_launch(void* const* d_in, const int* in_sizes, int n_in,
                              void* d_out, int out_size, void* d_ws, size_t ws_size,
                              hipStream_t stream)
{
    (void)in_sizes; (void)n_in; (void)out_size;
    const float* sequence = (const float*)d_in[0];
    const float* text     = (const float*)d_in[1];
    const __half* k_caches = (const __half*)d_in[2];
    const __half* v_caches = (const __half*)d_in[3];
    const int* steps      = (const int*)d_in[4];
    const float* bos      = (const float*)d_in[5];
    const float* W_in     = (const float*)d_in[6];
    const float* b_in     = (const float*)d_in[7];
    const float* ln1_w    = (const float*)d_in[8];
    const float* ln1_b    = (const float*)d_in[9];
    const float* Wqkv     = (const float*)d_in[10];
    const float* Wo       = (const float*)d_in[11];
    const float* ln2_w    = (const float*)d_in[12];
    const float* ln2_b    = (const float*)d_in[13];
    const float* W1       = (const float*)d_in[14];
    const float* b1       = (const float*)d_in[15];
    const float* W2       = (const float*)d_in[16];
    const float* b2       = (const float*)d_in[17];
    const float* outn_w   = (const float*)d_in[18];
    const float* outn_b   = (const float*)d_in[19];
    const float* W_eos    = (const float*)d_in[20];
    const float* b_eos    = (const float*)d_in[21];

    float* out = (float*)d_out;
    const size_t cacheN = (size_t)NUM_LAYERS * MAX_SEQ * DM;  // 25165824
    float* out_k = out + 1025;
    float* out_v = out_k + cacheN;
    const size_t steps_off = 1025 + 2 * cacheN;

    float* ws = (float*)d_ws;
    float* x        = ws;
    float* h        = x + (size_t)LSEQ * DM;
    float* q_buf    = h + (size_t)LSEQ * DM;
    float* attn_out = q_buf + (size_t)LSEQ * DM;
    float* big      = attn_out + (size_t)LSEQ * DM;
    float* ws_end   = big + (size_t)LSEQ * DFF;   // 4,456,448 floats

    // bf16 weight region
    __bf16* wb = (__bf16*)ws_end;
    const size_t szQkv = (size_t)3 * DM * DM;       // per layer (transposed)
    const size_t szO   = (size_t)DM * DM;
    const size_t szW1  = (size_t)DM * DFF;
    const size_t szW2  = (size_t)DFF * DM;
    __bf16* WqkvT = wb;
    __bf16* WoT   = WqkvT + szQkv * NUM_LAYERS;
    __bf16* W1T   = WoT   + szO   * NUM_LAYERS;
    __bf16* W2T   = W1T   + szW1  * NUM_LAYERS;
    const size_t need_bytes = (size_t)(ws_end - ws) * 4 +
        (szQkv + szO + szW1 + szW2) * NUM_LAYERS * sizeof(__bf16);
    const bool use_bt = ws_size >= need_bytes;

    cache_convert_kernel<<<2048, 256, 0, stream>>>(
        (const uint4*)k_caches, (const uint4*)v_caches,
        (float4*)out_k, (float4*)out_v, (int)(cacheN / 8));
    build_x_kernel<<<LSEQ, 256, 0, stream>>>(text, sequence, bos, W_in, b_in, x);

    if (use_bt) {
        transpose_cast_kernel<<<dim3(3 * DM / 32, DM / 32, 6), 256, 0, stream>>>(Wqkv, WqkvT, DM, 3 * DM);
        transpose_cast_kernel<<<dim3(DM / 32, DM / 32, 6), 256, 0, stream>>>(Wo, WoT, DM, DM);
        transpose_cast_kernel<<<dim3(DFF / 32, DM / 32, 6), 256, 0, stream>>>(W1, W1T, DM, DFF);
        transpose_cast_kernel<<<dim3(DM / 32, DFF / 32, 6), 256, 0, stream>>>(W2, W2T, DFF, DM);
    }

    for (int i = 0; i < NUM_LAYERS; ++i) {
        float* kci = out_k + (size_t)i * MAX_SEQ * DM;
        float* vci = out_v + (size_t)i * MAX_SEQ * DM;
        ln_kernel<<<LSEQ, 256, 0, stream>>>(x, ln1_w + i * DM, ln1_b + i * DM, h);
        if (use_bt) {
            gemm_bt_kernel<<<dim3(24, 9, 1), 256, 0, stream>>>(
                h, WqkvT + i * szQkv, big, nullptr, nullptr, LSEQ, 3 * DM, DM, DM, 0, 0);
        } else {
            gemm_mfma_kernel<<<dim3(24, 5), 256, 0, stream>>>(
                h, Wqkv + i * szQkv, big, nullptr, nullptr, LSEQ, 3 * DM, DM, 0);
        }
        rope_store_kernel<<<LSEQ, 256, 0, stream>>>(big, q_buf, kci, vci, steps, i);
        attn_flash_kernel<<<dim3(9, NH), 256, 0, stream>>>(q_buf, kci, vci, attn_out, steps, i);
        if (use_bt) {
            gemm_bt_kernel<<<dim3(8, 9, 2), 256, 0, stream>>>(
                attn_out, WoT + i * szO, x, nullptr, nullptr, LSEQ, DM, DM, DM / 2, 0, 1);
        } else {
            gemm_mfma_kernel<<<dim3(8, 5), 256, 0, stream>>>(
                attn_out, Wo + i * szO, x, nullptr, x, LSEQ, DM, DM, 0);
        }
        ln_kernel<<<LSEQ, 256, 0, stream>>>(x, ln2_w + i * DM, ln2_b + i * DM, h);
        if (use_bt) {
            gemm_bt_kernel<<<dim3(32, 9, 1), 256, 0, stream>>>(
                h, W1T + i * szW1, big, b1 + i * DFF, nullptr, LSEQ, DFF, DM, DM, 1, 0);
            gemm_bt_kernel<<<dim3(8, 9, 4), 256, 0, stream>>>(
                big, W2T + i * szW2, x, b2 + i * DM, nullptr, LSEQ, DM, DFF, DFF / 4, 0, 1);
        } else {
            gemm_mfma_kernel<<<dim3(32, 5), 256, 0, stream>>>(
                h, W1 + i * szW1, big, b1 + i * DFF, nullptr, LSEQ, DFF, DM, 1);
            gemm_mfma_kernel<<<dim3(8, 5), 256, 0, stream>>>(
                big, W2 + i * szW2, x, b2 + i * DM, x, LSEQ, DM, DFF, 0);
        }
    }
    final_kernel<<<1, 256, 0, stream>>>(x, outn_w, outn_b, W_eos, b_eos, steps, out, steps_off);
}